// Round 10
// baseline (12323.834 us; speedup 1.0000x reference)
//
#include <hip/hip_runtime.h>
#include <hip/hip_bf16.h>

typedef __attribute__((ext_vector_type(4))) float f4;
typedef __attribute__((ext_vector_type(4))) float f32x4;
typedef __attribute__((ext_vector_type(8))) short bf16x8;
typedef unsigned long long ull;

// ---------------- workspace layout (bytes) ----------------
#define OFF_XCAT   0ull                 // ushort [1024][128][512]  time-major LSTM input
#define OFF_WCAT   134217728ull         // ushort [2048][1024]      packed LSTM weights
#define OFF_BIAS   138412032ull         // float  [2048]
#define OFF_HW     138420224ull         // uint   [2][8][16][512]   tagged h words: (h_bf16<<16)|step_tag
#define OFF_CTR    138944512ull         // uint   [256]             counters/diag
#define WS_NEED    138945536ull

__device__ inline unsigned short f2bf(float x){
  unsigned u = __float_as_uint(x);
  unsigned r = (u + 0x7FFFu + ((u >> 16) & 1u)) >> 16;   // RNE
  return (unsigned short)r;
}
__device__ inline float bf2f(unsigned short s){ return __uint_as_float(((unsigned)s) << 16); }

// ---------------- diagnostic fill (absmax is the debug channel) ----------------
__global__ void __launch_bounds__(256) diag_write(float* out, float val){
  out[blockIdx.x * 256 + threadIdx.x] = val;
}

// ---------------- weight repack ----------------
__global__ void __launch_bounds__(256) prep_w(
    const float* Wii, const float* Wif, const float* Wig, const float* Wio,
    const float* Whi, const float* Whf, const float* Whg, const float* Who,
    const float* Bii, const float* Bif, const float* Big, const float* Bio,
    const float* Bhi, const float* Bhf, const float* Bhg, const float* Bho,
    unsigned short* Wcat, float* bias_cat){
  int e = blockIdx.x * 256 + threadIdx.x;        // < 2048*1024
  int col = e >> 10, k = e & 1023;
  int u = col >> 2, g = col & 3;
  float v;
  if (k < 512){
    const float* p = (g==0)?Wii:((g==1)?Wif:((g==2)?Wig:Wio));
    v = p[u*512 + k];
  } else {
    const float* p = (g==0)?Whi:((g==1)?Whf:((g==2)?Whg:Who));
    v = p[u*512 + (k-512)];
  }
  Wcat[e] = f2bf(v);
  if (e < 2048){
    int u2 = e >> 2, g2 = e & 3;
    const float* bx = (g2==0)?Bii:((g2==1)?Bif:((g2==2)?Big:Bio));
    const float* bh = (g2==0)?Bhi:((g2==1)?Bhf:((g2==2)?Bhg:Bho));
    bias_cat[e] = bx[u2] + bh[u2];
  }
}

// ---------------- fused stage A (proven r2/r3) ----------------
__global__ void __launch_bounds__(256) stageA_fused(
    const float* __restrict__ xnum, const int* __restrict__ xstate,
    const float* __restrict__ emb,
    const float* __restrict__ num_w0, const float* __restrict__ num_b0,
    const float* __restrict__ num_w1, const float* __restrict__ num_b1,
    const float* __restrict__ st_w0,  const float* __restrict__ st_b0,
    const float* __restrict__ st_w1,  const float* __restrict__ st_b1,
    unsigned short* __restrict__ Xcat){
  __shared__ float Wt[32*256];
  __shared__ float xb[16*68];
  __shared__ float h1[16*260];
  int tid = threadIdx.x;
  long tok0 = (long)blockIdx.x * 16;
  int tg = tid >> 6, c4 = tid & 63;

  #pragma unroll 1
  for (int br = 0; br < 2; ++br){
    const float* W0 = br ? st_w0 : num_w0;
    const float* b0 = br ? st_b0 : num_b0;
    const float* W1 = br ? st_w1 : num_w1;
    const float* b1 = br ? st_b1 : num_b1;

    __syncthreads();
    if (br == 0){
      int tk = tid >> 4, q = tid & 15;
      f4 v = *(const f4*)(xnum + (tok0+tk)*64 + q*4);
      float* d = xb + tk*68 + q*4;
      d[0]=v.x; d[1]=v.y; d[2]=v.z; d[3]=v.w;
    } else {
      int tk = tid >> 4, j = tid & 15;
      int idx = xstate[(tok0+tk)*16 + j];
      f4 v = *(const f4*)(emb + idx*4);
      float* d = xb + tk*68 + j*4;
      d[0]=v.x; d[1]=v.y; d[2]=v.z; d[3]=v.w;
    }

    float acc[4][4];
    { f4 bv = *(const f4*)(b0 + c4*4);
      #pragma unroll
      for (int j=0;j<4;j++){ acc[j][0]=bv.x; acc[j][1]=bv.y; acc[j][2]=bv.z; acc[j][3]=bv.w; } }
    for (int kh=0; kh<2; ++kh){
      __syncthreads();
      { int c = tid;
        const f4* src = (const f4*)(W0 + c*64 + kh*32);
        #pragma unroll
        for (int q=0;q<8;q++){
          f4 v = src[q];
          Wt[(q*4+0)*256 + c] = v.x; Wt[(q*4+1)*256 + c] = v.y;
          Wt[(q*4+2)*256 + c] = v.z; Wt[(q*4+3)*256 + c] = v.w;
        }
      }
      __syncthreads();
      for (int kq=0; kq<8; kq++){
        int k0 = kh*32 + kq*4;
        f4 a0 = *(const f4*)(xb + (tg*4+0)*68 + k0);
        f4 a1 = *(const f4*)(xb + (tg*4+1)*68 + k0);
        f4 a2 = *(const f4*)(xb + (tg*4+2)*68 + k0);
        f4 a3 = *(const f4*)(xb + (tg*4+3)*68 + k0);
        f4 w0 = *(const f4*)(Wt + (kq*4+0)*256 + c4*4);
        f4 w1 = *(const f4*)(Wt + (kq*4+1)*256 + c4*4);
        f4 w2 = *(const f4*)(Wt + (kq*4+2)*256 + c4*4);
        f4 w3 = *(const f4*)(Wt + (kq*4+3)*256 + c4*4);
        #pragma unroll
        for (int j=0;j<4;j++){
          f4 a = (j==0)?a0:((j==1)?a1:((j==2)?a2:a3));
          #pragma unroll
          for (int d=0; d<4; d++)
            acc[j][d] += a.x*w0[d] + a.y*w1[d] + a.z*w2[d] + a.w*w3[d];
        }
      }
    }
    #pragma unroll
    for (int j=0;j<4;j++){
      float v0=fmaxf(acc[j][0],0.f), v1=fmaxf(acc[j][1],0.f);
      float v2=fmaxf(acc[j][2],0.f), v3=fmaxf(acc[j][3],0.f);
      float s1 = v0+v1+v2+v3, s2 = v0*v0+v1*v1+v2*v2+v3*v3;
      for (int off=1; off<64; off<<=1){ s1 += __shfl_xor(s1, off); s2 += __shfl_xor(s2, off); }
      float mu = s1 * (1.f/256.f);
      float rs = rsqrtf(s2*(1.f/256.f) - mu*mu + 1e-5f);
      f4 o; o.x=(v0-mu)*rs; o.y=(v1-mu)*rs; o.z=(v2-mu)*rs; o.w=(v3-mu)*rs;
      *(f4*)(h1 + (tg*4+j)*260 + c4*4) = o;
    }

    float ac2[4][4];
    { f4 bv = *(const f4*)(b1 + c4*4);
      #pragma unroll
      for (int j=0;j<4;j++){ ac2[j][0]=bv.x; ac2[j][1]=bv.y; ac2[j][2]=bv.z; ac2[j][3]=bv.w; } }
    for (int kh=0; kh<8; ++kh){
      __syncthreads();
      { int c = tid;
        const f4* src = (const f4*)(W1 + c*256 + kh*32);
        #pragma unroll
        for (int q=0;q<8;q++){
          f4 v = src[q];
          Wt[(q*4+0)*256 + c] = v.x; Wt[(q*4+1)*256 + c] = v.y;
          Wt[(q*4+2)*256 + c] = v.z; Wt[(q*4+3)*256 + c] = v.w;
        }
      }
      __syncthreads();
      for (int kq=0; kq<8; kq++){
        int k0 = kh*32 + kq*4;
        f4 a0 = *(const f4*)(h1 + (tg*4+0)*260 + k0);
        f4 a1 = *(const f4*)(h1 + (tg*4+1)*260 + k0);
        f4 a2 = *(const f4*)(h1 + (tg*4+2)*260 + k0);
        f4 a3 = *(const f4*)(h1 + (tg*4+3)*260 + k0);
        f4 w0 = *(const f4*)(Wt + (kq*4+0)*256 + c4*4);
        f4 w1 = *(const f4*)(Wt + (kq*4+1)*256 + c4*4);
        f4 w2 = *(const f4*)(Wt + (kq*4+2)*256 + c4*4);
        f4 w3 = *(const f4*)(Wt + (kq*4+3)*256 + c4*4);
        #pragma unroll
        for (int j=0;j<4;j++){
          f4 a = (j==0)?a0:((j==1)?a1:((j==2)?a2:a3));
          #pragma unroll
          for (int d=0; d<4; d++)
            ac2[j][d] += a.x*w0[d] + a.y*w1[d] + a.z*w2[d] + a.w*w3[d];
        }
      }
    }
    #pragma unroll
    for (int j=0;j<4;j++){
      float v0=fmaxf(ac2[j][0],0.f), v1=fmaxf(ac2[j][1],0.f);
      float v2=fmaxf(ac2[j][2],0.f), v3=fmaxf(ac2[j][3],0.f);
      float s1 = v0+v1+v2+v3, s2 = v0*v0+v1*v1+v2*v2+v3*v3;
      for (int off=1; off<64; off<<=1){ s1 += __shfl_xor(s1, off); s2 += __shfl_xor(s2, off); }
      float mu = s1 * (1.f/256.f);
      float rs = rsqrtf(s2*(1.f/256.f) - mu*mu + 1e-5f);
      long tok = tok0 + tg*4 + j;
      long bb = tok >> 10, ss = tok & 1023;
      unsigned short* o = Xcat + (ss*128 + bb)*512 + br*256 + c4*4;
      unsigned lo = (unsigned)f2bf((v0-mu)*rs) | ((unsigned)f2bf((v1-mu)*rs) << 16);
      unsigned hi = (unsigned)f2bf((v2-mu)*rs) | ((unsigned)f2bf((v3-mu)*rs) << 16);
      ((unsigned*)o)[0] = lo; ((unsigned*)o)[1] = hi;
    }
  }
}

// ---------------- persistent LSTM kernel (tagged-word exchange, LDS h-weights) ----------------
// grid = 256 WGs x 256 thr. group g = blockIdx&7 (16 batch rows), member m = blockIdx>>3.
// h word = (h_bf16<<16)|step_tag: data and signal fused -> no producer drain, no flag,
// consumer polls its own 32 words until tags==t. h-weights live in dynamic LDS (64KB).
__global__ void __launch_bounds__(256, 1) lstm_pk(
    const unsigned short* __restrict__ Xcat,
    const unsigned short* __restrict__ Wcat,
    const float* __restrict__ bias_cat,
    unsigned int* __restrict__ hw,
    unsigned int* __restrict__ ctr){
  __shared__ __align__(16) char actb[32768];   // h act tiles, double buffer
  extern __shared__ __align__(16) char wlds[]; // 64KB: h-part weights (k=512..1023)
  __shared__ int okf, sdead;
  int tid = threadIdx.x;
  int lane = tid & 63, w = tid >> 6;
  int g = blockIdx.x & 7, m = blockIdx.x >> 3;

  // ---- stage h-weights into LDS (4096 x 16B chunks, swizzled like actb) ----
  #pragma unroll
  for (int i=0;i<16;i++){
    int c16 = tid + (i<<8);               // 0..4095
    int ww  = c16 >> 10;                  // wave
    int col = (c16 >> 6) & 15;            // lane&15 analog
    int kc  = c16 & 63;                   // 16B chunk within 1024B col-slice
    const bf16x8* src = (const bf16x8*)(Wcat + (long)(64*m + 16*ww + col)*1024 + 512 + kc*8);
    int off = ((ww<<14) + (col<<10) + (kc<<4)) ^ ((col & 7) << 4);
    *(bf16x8*)(wlds + off) = *src;
  }

  // ---- x-part weights (k=0..511) in registers ----
  int colg = 64*m + 16*w + (lane & 15);
  bf16x8 wfx[16];
  {
    const bf16x8* wsrc = (const bf16x8*)(Wcat + (long)colg*1024 + (lane>>4)*8);
    #pragma unroll
    for (int s=0;s<16;s++) wfx[s] = wsrc[s*4];
    #pragma unroll
    for (int s=0;s<16;s++) asm volatile("" : "+v"(wfx[s]));
  }
  int cb = 64*m + 16*w + 4*(lane>>4);
  f32x4 bias4;
  bias4.x = bias_cat[cb+0]; bias4.y = bias_cat[cb+1];
  bias4.z = bias_cat[cb+2]; bias4.w = bias_cat[cb+3];

  // co-residency check (bounded; no hang); barrier also covers wlds staging
  if (tid == 0){
    __hip_atomic_fetch_add(&ctr[255], 1u, __ATOMIC_RELAXED, __HIP_MEMORY_SCOPE_AGENT);
    unsigned v = 0; int it = 0;
    do {
      v = __hip_atomic_load(&ctr[255], __ATOMIC_RELAXED, __HIP_MEMORY_SCOPE_AGENT);
      if (v >= 256u) break;
      __builtin_amdgcn_s_sleep(8);
    } while (++it < 2000000);
    okf = (v >= 256u) ? 1 : 0;
    sdead = 0;
  }
  __syncthreads();
  if (!okf) return;

  float cst = 0.f;
  int r16 = tid >> 4, q16 = tid & 15;
  int wbase = (w<<14) + ((lane&15)<<10);
  int wswz  = ((lane&15)&7)<<4;

  // prologue: x-part for t=0
  f32x4 acc0, acc1;
  {
    bf16x8 xf[16];
    const bf16x8* xsrc = (const bf16x8*)(Xcat + ((long)0*128 + g*16 + (lane&15))*512 + (lane>>4)*8);
    #pragma unroll
    for (int s=0;s<16;s++) xf[s] = xsrc[s*4];
    acc0 = bias4;
    acc1.x=0.f; acc1.y=0.f; acc1.z=0.f; acc1.w=0.f;
    #pragma unroll
    for (int s=0;s<16;s+=2){
      acc0 = __builtin_amdgcn_mfma_f32_16x16x32_bf16(wfx[s],   xf[s],   acc0, 0, 0, 0);
      acc1 = __builtin_amdgcn_mfma_f32_16x16x32_bf16(wfx[s+1], xf[s+1], acc1, 0, 0, 0);
    }
  }

  #pragma unroll 1
  for (int t=0; t<1024; ++t){
    // ---- poll own 32 tagged words (units 32*q16..+31 of row r16), then stage to LDS ----
    {
      const unsigned int* hp = hw + ((long)(t&1)*65536) + g*8192 + r16*512 + q16*32;
      unsigned hv[32];
      if (t > 0){
        unsigned tt = (unsigned)t & 0xFFFFu; int itc = 0;
        for (;;){
          #pragma unroll
          for (int i=0;i<32;i++)
            hv[i] = __hip_atomic_load(&hp[i], __ATOMIC_RELAXED, __HIP_MEMORY_SCOPE_AGENT);
          unsigned bad = 0;
          #pragma unroll
          for (int i=0;i<32;i++) bad |= (hv[i] & 0xFFFFu) ^ tt;
          if (!bad) break;
          if ((itc & 31) == 31 && *(volatile int*)&sdead) break;
          if (++itc > 100000){
            *(volatile int*)&sdead = 1;
            __hip_atomic_store(&ctr[252], (unsigned)t, __ATOMIC_RELAXED, __HIP_MEMORY_SCOPE_AGENT);
            break;
          }
        }
      } else {
        #pragma unroll
        for (int i=0;i<32;i++)
          hv[i] = __hip_atomic_load(&hp[i], __ATOMIC_RELAXED, __HIP_MEMORY_SCOPE_AGENT);
      }
      // pack high-16 data into bf16 pair words, write swizzled LDS
      char* hl = actb + (t&1)*16384;
      #pragma unroll
      for (int i=0;i<8;i++){
        unsigned p0 = (hv[4*i+0] >> 16) | (hv[4*i+1] & 0xFFFF0000u);
        unsigned p1 = (hv[4*i+2] >> 16) | (hv[4*i+3] & 0xFFFF0000u);
        ull pp = (ull)p0 | ((ull)p1 << 32);
        int byt = (r16*1024 + q16*64 + i*8) ^ ((r16 & 7) << 4);
        *(ull*)(hl + byt) = pp;
      }
    }
    __syncthreads();
    if (*(volatile int*)&sdead) break;
    // ---- h-part MFMAs (k=512..1023), weights from LDS ----
    {
      const char* hl = actb + (t&1)*16384;
      #pragma unroll
      for (int s=0;s<16;s+=2){
        bf16x8 wb0 = *(const bf16x8*)(wlds + ((wbase + s*64     + ((lane>>4)<<4)) ^ wswz));
        bf16x8 wb1 = *(const bf16x8*)(wlds + ((wbase + (s+1)*64 + ((lane>>4)<<4)) ^ wswz));
        int by0 = (((lane&15)<<10) + s*64     + ((lane>>4)<<4)) ^ wswz;
        int by1 = (((lane&15)<<10) + (s+1)*64 + ((lane>>4)<<4)) ^ wswz;
        bf16x8 b0 = *(const bf16x8*)(hl + by0);
        bf16x8 b1 = *(const bf16x8*)(hl + by1);
        acc0 = __builtin_amdgcn_mfma_f32_16x16x32_bf16(wb0, b0, acc0, 0, 0, 0);
        acc1 = __builtin_amdgcn_mfma_f32_16x16x32_bf16(wb1, b1, acc1, 0, 0, 0);
      }
    }
    // ---- gates & state update ----
    float gi = acc0.x + acc1.x, gf = acc0.y + acc1.y;
    float gg = acc0.z + acc1.z, go = acc0.w + acc1.w;
    float iv = 1.f / (1.f + __expf(-gi));
    float fv = 1.f / (1.f + __expf(-gf));
    float e2 = __expf(-2.f * gg);
    float gv = (1.f - e2) / (1.f + e2);
    float ov = 1.f / (1.f + __expf(-go));
    cst = fv * cst + iv * gv;
    float e2c = __expf(-2.f * cst);
    float hout = ov * (1.f - e2c) / (1.f + e2c);
    // ---- publish h_{t+1} as tagged word (fire-and-forget; no drain, no flag) ----
    {
      unsigned short hb16 = f2bf(hout);
      int unit = 16*m + 4*w + (lane >> 4);
      int row  = lane & 15;
      unsigned word = ((unsigned)hb16 << 16) | ((unsigned)(t+1) & 0xFFFFu);
      unsigned int* dst = hw + ((long)((t+1)&1)*65536) + g*8192 + row*512 + unit;
      __hip_atomic_store(dst, word, __ATOMIC_RELAXED, __HIP_MEMORY_SCOPE_AGENT);
    }
    // ---- x-part for t+1 (overlaps store visibility across the group) ----
    {
      int tn = (t < 1023) ? (t+1) : 1023;
      bf16x8 xf[16];
      const bf16x8* xsrc = (const bf16x8*)(Xcat + ((long)tn*128 + g*16 + (lane&15))*512 + (lane>>4)*8);
      #pragma unroll
      for (int s=0;s<16;s++) xf[s] = xsrc[s*4];
      acc0 = bias4;
      acc1.x=0.f; acc1.y=0.f; acc1.z=0.f; acc1.w=0.f;
      #pragma unroll
      for (int s=0;s<16;s+=2){
        acc0 = __builtin_amdgcn_mfma_f32_16x16x32_bf16(wfx[s],   xf[s],   acc0, 0, 0, 0);
        acc1 = __builtin_amdgcn_mfma_f32_16x16x32_bf16(wfx[s+1], xf[s+1], acc1, 0, 0, 0);
      }
    }
  }

  __syncthreads();
  if (tid == 0 && !sdead)
    __hip_atomic_fetch_add(&ctr[251], 1u, __ATOMIC_RELAXED, __HIP_MEMORY_SCOPE_AGENT);
}

// ---------------- output projection (reads tagged words, buffer 0) ----------------
__global__ void __launch_bounds__(256) out_gemm(
    const unsigned int* __restrict__ hw, const unsigned int* __restrict__ ctr,
    const float* __restrict__ out_w, const float* __restrict__ out_b,
    float* __restrict__ out){
  unsigned done = ctr[251], arriv = ctr[255], dead = ctr[252];
  if (dead != 0u || done != 256u){
    float v = dead ? (20000.f + (float)dead) : (10000.f + (float)arriv);
    if (threadIdx.x < 32) out[blockIdx.x*32 + threadIdx.x] = v;
    return;
  }
  __shared__ float part[8][32];
  int b = blockIdx.x;
  int g = b >> 4, r = b & 15;
  const unsigned int* hrow = hw + (long)g*8192 + r*512;   // parity 0 holds h after step 1023
  int col = threadIdx.x & 31, p = threadIdx.x >> 5;
  float s = 0.f;
  for (int u = p*64; u < p*64 + 64; ++u)
    s += bf2f((unsigned short)(hrow[u] >> 16)) * out_w[col*512 + u];
  part[p][col] = s;
  __syncthreads();
  if (p == 0){
    float t = out_b[col];
    #pragma unroll
    for (int i=0;i<8;i++) t += part[i][col];
    out[b*32 + col] = t;
  }
}

extern "C" void kernel_launch(void* const* d_in, const int* in_sizes, int n_in,
                              void* d_out, int out_size, void* d_ws, size_t ws_size,
                              hipStream_t stream){
  const float* x_num   = (const float*)d_in[0];
  const int*   x_state = (const int*)d_in[1];
  const float* num_w0  = (const float*)d_in[2];
  const float* num_b0  = (const float*)d_in[3];
  const float* num_w1  = (const float*)d_in[4];
  const float* num_b1  = (const float*)d_in[5];
  const float* emb     = (const float*)d_in[6];
  const float* st_w0   = (const float*)d_in[7];
  const float* st_b0   = (const float*)d_in[8];
  const float* st_w1   = (const float*)d_in[9];
  const float* st_b1   = (const float*)d_in[10];
  const float* Wii = (const float*)d_in[11];
  const float* Whi = (const float*)d_in[12];
  const float* Wif = (const float*)d_in[13];
  const float* Whf = (const float*)d_in[14];
  const float* Wig = (const float*)d_in[15];
  const float* Whg = (const float*)d_in[16];
  const float* Wio = (const float*)d_in[17];
  const float* Who = (const float*)d_in[18];
  const float* Bii = (const float*)d_in[19];
  const float* Bhi = (const float*)d_in[20];
  const float* Bif = (const float*)d_in[21];
  const float* Bhf = (const float*)d_in[22];
  const float* Big = (const float*)d_in[23];
  const float* Bhg = (const float*)d_in[24];
  const float* Bio = (const float*)d_in[25];
  const float* Bho = (const float*)d_in[26];
  const float* out_w = (const float*)d_in[27];
  const float* out_b = (const float*)d_in[28];

  float* out = (float*)d_out;

  // sentinel: if later launches silently fail, absmax ~= 50000
  diag_write<<<16, 256, 0, stream>>>(out, 50000.f);

  if (ws_size < WS_NEED){
    diag_write<<<16, 256, 0, stream>>>(out, 100000.f + (float)(ws_size >> 20));
    return;
  }

  char* ws = (char*)d_ws;
  unsigned short* Xcat = (unsigned short*)(ws + OFF_XCAT);
  unsigned short* Wcat = (unsigned short*)(ws + OFF_WCAT);
  float* bias_cat      = (float*)(ws + OFF_BIAS);
  unsigned int* hw     = (unsigned int*)(ws + OFF_HW);
  unsigned int* ctr    = (unsigned int*)(ws + OFF_CTR);

  // zero tagged-word h buffer + counters every call (tags restart at 1)
  hipMemsetAsync(ws + OFF_HW, 0, 524288 + 1024, stream);

  prep_w<<<8192, 256, 0, stream>>>(Wii, Wif, Wig, Wio, Whi, Whf, Whg, Who,
                                   Bii, Bif, Big, Bio, Bhi, Bhf, Bhg, Bho,
                                   Wcat, bias_cat);

  stageA_fused<<<8192, 256, 0, stream>>>(x_num, x_state, emb,
                                         num_w0, num_b0, num_w1, num_b1,
                                         st_w0, st_b0, st_w1, st_b1, Xcat);

  hipFuncSetAttribute((const void*)lstm_pk,
                      hipFuncAttributeMaxDynamicSharedMemorySize, 65536);
  lstm_pk<<<256, 256, 65536, stream>>>(Xcat, Wcat, bias_cat, hw, ctr);

  out_gemm<<<128, 256, 0, stream>>>(hw, ctr, out_w, out_b, out);
}

// Round 11
// 5262.327 us; speedup vs baseline: 2.3419x; 2.3419x over previous
//
#include <hip/hip_runtime.h>
#include <hip/hip_bf16.h>

typedef __attribute__((ext_vector_type(4))) float f4;
typedef __attribute__((ext_vector_type(4))) float f32x4;
typedef __attribute__((ext_vector_type(8))) short bf16x8;
typedef __attribute__((ext_vector_type(4))) unsigned u32x4;
typedef unsigned long long ull;

// ---------------- workspace layout (bytes) ----------------
#define OFF_XCAT   0ull                 // ushort [1024][128][512]  time-major LSTM input
#define OFF_WCAT   134217728ull         // ushort [2048][1024]      packed LSTM weights
#define OFF_BIAS   138412032ull         // float  [2048]
#define OFF_HW     138420224ull         // uint   [2][8][16][512]   tagged h words: (h_bf16<<16)|step_tag
#define OFF_CTR    138944512ull         // uint   [256]             counters/diag
#define WS_NEED    138945536ull

__device__ inline unsigned short f2bf(float x){
  unsigned u = __float_as_uint(x);
  unsigned r = (u + 0x7FFFu + ((u >> 16) & 1u)) >> 16;   // RNE
  return (unsigned short)r;
}
__device__ inline float bf2f(unsigned short s){ return __uint_as_float(((unsigned)s) << 16); }

// ---------------- diagnostic fill (absmax is the debug channel) ----------------
__global__ void __launch_bounds__(256) diag_write(float* out, float val){
  out[blockIdx.x * 256 + threadIdx.x] = val;
}

// ---------------- weight repack ----------------
__global__ void __launch_bounds__(256) prep_w(
    const float* Wii, const float* Wif, const float* Wig, const float* Wio,
    const float* Whi, const float* Whf, const float* Whg, const float* Who,
    const float* Bii, const float* Bif, const float* Big, const float* Bio,
    const float* Bhi, const float* Bhf, const float* Bhg, const float* Bho,
    unsigned short* Wcat, float* bias_cat){
  int e = blockIdx.x * 256 + threadIdx.x;        // < 2048*1024
  int col = e >> 10, k = e & 1023;
  int u = col >> 2, g = col & 3;
  float v;
  if (k < 512){
    const float* p = (g==0)?Wii:((g==1)?Wif:((g==2)?Wig:Wio));
    v = p[u*512 + k];
  } else {
    const float* p = (g==0)?Whi:((g==1)?Whf:((g==2)?Whg:Who));
    v = p[u*512 + (k-512)];
  }
  Wcat[e] = f2bf(v);
  if (e < 2048){
    int u2 = e >> 2, g2 = e & 3;
    const float* bx = (g2==0)?Bii:((g2==1)?Bif:((g2==2)?Big:Bio));
    const float* bh = (g2==0)?Bhi:((g2==1)?Bhf:((g2==2)?Bhg:Bho));
    bias_cat[e] = bx[u2] + bh[u2];
  }
}

// ---------------- fused stage A (proven r2/r3) ----------------
__global__ void __launch_bounds__(256) stageA_fused(
    const float* __restrict__ xnum, const int* __restrict__ xstate,
    const float* __restrict__ emb,
    const float* __restrict__ num_w0, const float* __restrict__ num_b0,
    const float* __restrict__ num_w1, const float* __restrict__ num_b1,
    const float* __restrict__ st_w0,  const float* __restrict__ st_b0,
    const float* __restrict__ st_w1,  const float* __restrict__ st_b1,
    unsigned short* __restrict__ Xcat){
  __shared__ float Wt[32*256];
  __shared__ float xb[16*68];
  __shared__ float h1[16*260];
  int tid = threadIdx.x;
  long tok0 = (long)blockIdx.x * 16;
  int tg = tid >> 6, c4 = tid & 63;

  #pragma unroll 1
  for (int br = 0; br < 2; ++br){
    const float* W0 = br ? st_w0 : num_w0;
    const float* b0 = br ? st_b0 : num_b0;
    const float* W1 = br ? st_w1 : num_w1;
    const float* b1 = br ? st_b1 : num_b1;

    __syncthreads();
    if (br == 0){
      int tk = tid >> 4, q = tid & 15;
      f4 v = *(const f4*)(xnum + (tok0+tk)*64 + q*4);
      float* d = xb + tk*68 + q*4;
      d[0]=v.x; d[1]=v.y; d[2]=v.z; d[3]=v.w;
    } else {
      int tk = tid >> 4, j = tid & 15;
      int idx = xstate[(tok0+tk)*16 + j];
      f4 v = *(const f4*)(emb + idx*4);
      float* d = xb + tk*68 + j*4;
      d[0]=v.x; d[1]=v.y; d[2]=v.z; d[3]=v.w;
    }

    float acc[4][4];
    { f4 bv = *(const f4*)(b0 + c4*4);
      #pragma unroll
      for (int j=0;j<4;j++){ acc[j][0]=bv.x; acc[j][1]=bv.y; acc[j][2]=bv.z; acc[j][3]=bv.w; } }
    for (int kh=0; kh<2; ++kh){
      __syncthreads();
      { int c = tid;
        const f4* src = (const f4*)(W0 + c*64 + kh*32);
        #pragma unroll
        for (int q=0;q<8;q++){
          f4 v = src[q];
          Wt[(q*4+0)*256 + c] = v.x; Wt[(q*4+1)*256 + c] = v.y;
          Wt[(q*4+2)*256 + c] = v.z; Wt[(q*4+3)*256 + c] = v.w;
        }
      }
      __syncthreads();
      for (int kq=0; kq<8; kq++){
        int k0 = kh*32 + kq*4;
        f4 a0 = *(const f4*)(xb + (tg*4+0)*68 + k0);
        f4 a1 = *(const f4*)(xb + (tg*4+1)*68 + k0);
        f4 a2 = *(const f4*)(xb + (tg*4+2)*68 + k0);
        f4 a3 = *(const f4*)(xb + (tg*4+3)*68 + k0);
        f4 w0 = *(const f4*)(Wt + (kq*4+0)*256 + c4*4);
        f4 w1 = *(const f4*)(Wt + (kq*4+1)*256 + c4*4);
        f4 w2 = *(const f4*)(Wt + (kq*4+2)*256 + c4*4);
        f4 w3 = *(const f4*)(Wt + (kq*4+3)*256 + c4*4);
        #pragma unroll
        for (int j=0;j<4;j++){
          f4 a = (j==0)?a0:((j==1)?a1:((j==2)?a2:a3));
          #pragma unroll
          for (int d=0; d<4; d++)
            acc[j][d] += a.x*w0[d] + a.y*w1[d] + a.z*w2[d] + a.w*w3[d];
        }
      }
    }
    #pragma unroll
    for (int j=0;j<4;j++){
      float v0=fmaxf(acc[j][0],0.f), v1=fmaxf(acc[j][1],0.f);
      float v2=fmaxf(acc[j][2],0.f), v3=fmaxf(acc[j][3],0.f);
      float s1 = v0+v1+v2+v3, s2 = v0*v0+v1*v1+v2*v2+v3*v3;
      for (int off=1; off<64; off<<=1){ s1 += __shfl_xor(s1, off); s2 += __shfl_xor(s2, off); }
      float mu = s1 * (1.f/256.f);
      float rs = rsqrtf(s2*(1.f/256.f) - mu*mu + 1e-5f);
      f4 o; o.x=(v0-mu)*rs; o.y=(v1-mu)*rs; o.z=(v2-mu)*rs; o.w=(v3-mu)*rs;
      *(f4*)(h1 + (tg*4+j)*260 + c4*4) = o;
    }

    float ac2[4][4];
    { f4 bv = *(const f4*)(b1 + c4*4);
      #pragma unroll
      for (int j=0;j<4;j++){ ac2[j][0]=bv.x; ac2[j][1]=bv.y; ac2[j][2]=bv.z; ac2[j][3]=bv.w; } }
    for (int kh=0; kh<8; ++kh){
      __syncthreads();
      { int c = tid;
        const f4* src = (const f4*)(W1 + c*256 + kh*32);
        #pragma unroll
        for (int q=0;q<8;q++){
          f4 v = src[q];
          Wt[(q*4+0)*256 + c] = v.x; Wt[(q*4+1)*256 + c] = v.y;
          Wt[(q*4+2)*256 + c] = v.z; Wt[(q*4+3)*256 + c] = v.w;
        }
      }
      __syncthreads();
      for (int kq=0; kq<8; kq++){
        int k0 = kh*32 + kq*4;
        f4 a0 = *(const f4*)(h1 + (tg*4+0)*260 + k0);
        f4 a1 = *(const f4*)(h1 + (tg*4+1)*260 + k0);
        f4 a2 = *(const f4*)(h1 + (tg*4+2)*260 + k0);
        f4 a3 = *(const f4*)(h1 + (tg*4+3)*260 + k0);
        f4 w0 = *(const f4*)(Wt + (kq*4+0)*256 + c4*4);
        f4 w1 = *(const f4*)(Wt + (kq*4+1)*256 + c4*4);
        f4 w2 = *(const f4*)(Wt + (kq*4+2)*256 + c4*4);
        f4 w3 = *(const f4*)(Wt + (kq*4+3)*256 + c4*4);
        #pragma unroll
        for (int j=0;j<4;j++){
          f4 a = (j==0)?a0:((j==1)?a1:((j==2)?a2:a3));
          #pragma unroll
          for (int d=0; d<4; d++)
            ac2[j][d] += a.x*w0[d] + a.y*w1[d] + a.z*w2[d] + a.w*w3[d];
        }
      }
    }
    #pragma unroll
    for (int j=0;j<4;j++){
      float v0=fmaxf(ac2[j][0],0.f), v1=fmaxf(ac2[j][1],0.f);
      float v2=fmaxf(ac2[j][2],0.f), v3=fmaxf(ac2[j][3],0.f);
      float s1 = v0+v1+v2+v3, s2 = v0*v0+v1*v1+v2*v2+v3*v3;
      for (int off=1; off<64; off<<=1){ s1 += __shfl_xor(s1, off); s2 += __shfl_xor(s2, off); }
      float mu = s1 * (1.f/256.f);
      float rs = rsqrtf(s2*(1.f/256.f) - mu*mu + 1e-5f);
      long tok = tok0 + tg*4 + j;
      long bb = tok >> 10, ss = tok & 1023;
      unsigned short* o = Xcat + (ss*128 + bb)*512 + br*256 + c4*4;
      unsigned lo = (unsigned)f2bf((v0-mu)*rs) | ((unsigned)f2bf((v1-mu)*rs) << 16);
      unsigned hi = (unsigned)f2bf((v2-mu)*rs) | ((unsigned)f2bf((v3-mu)*rs) << 16);
      ((unsigned*)o)[0] = lo; ((unsigned*)o)[1] = hi;
    }
  }
}

// ---------------- coalesced agent-scope poll load: 8 x dwordx4, sc1 ----------------
__device__ __forceinline__ void ld8x16_sc1(const unsigned* p, u32x4* v){
  asm volatile(
    "global_load_dwordx4 %0, %8, off sc1\n\t"
    "global_load_dwordx4 %1, %8, off offset:256 sc1\n\t"
    "global_load_dwordx4 %2, %8, off offset:512 sc1\n\t"
    "global_load_dwordx4 %3, %8, off offset:768 sc1\n\t"
    "global_load_dwordx4 %4, %8, off offset:1024 sc1\n\t"
    "global_load_dwordx4 %5, %8, off offset:1280 sc1\n\t"
    "global_load_dwordx4 %6, %8, off offset:1536 sc1\n\t"
    "global_load_dwordx4 %7, %8, off offset:1792 sc1\n\t"
    "s_waitcnt vmcnt(0)"
    : "=&v"(v[0]),"=&v"(v[1]),"=&v"(v[2]),"=&v"(v[3]),
      "=&v"(v[4]),"=&v"(v[5]),"=&v"(v[6]),"=&v"(v[7])
    : "v"(p) : "memory");
}

// ---------------- persistent LSTM kernel (tagged-word exchange, r9 structure) ----------------
// grid = 256 WGs x 256 thr. group g = blockIdx&7 (16 batch rows), member m = blockIdx>>3.
// h word = (h_bf16<<16)|step_tag. Publish = ONE relaxed agent store per lane (no drain,
// no flag). Consumers poll their 32 words via coalesced dwordx4 sc1 loads: detection IS
// data arrival. WG collectively polls all 8192 group words before its barrier ->
// 2-buffer parity reuse is race-free (publish is post-barrier).
__global__ void __launch_bounds__(256, 1) lstm_pk(
    const unsigned short* __restrict__ Xcat,
    const unsigned short* __restrict__ Wcat,
    const float* __restrict__ bias_cat,
    unsigned int* __restrict__ hw,
    unsigned int* __restrict__ ctr){
  __shared__ __align__(16) char actb[32768];   // h act tiles, double buffer (r9 layout)
  __shared__ int okf, sdead;
  int tid = threadIdx.x;
  int lane = tid & 63, w = tid >> 6;
  int g = blockIdx.x & 7, m = blockIdx.x >> 3;

  // stationary weights (L2-resident in practice): cols 64m+16w+(lane&15), k = s*32+(lane>>4)*8
  int colg = 64*m + 16*w + (lane & 15);
  bf16x8 wf[32];
  {
    const bf16x8* wsrc = (const bf16x8*)(Wcat + (long)colg*1024 + (lane>>4)*8);
    #pragma unroll
    for (int s=0;s<32;s++) wf[s] = wsrc[s*4];
  }
  int cb = 64*m + 16*w + 4*(lane>>4);
  f32x4 bias4;
  bias4.x = bias_cat[cb+0]; bias4.y = bias_cat[cb+1];
  bias4.z = bias_cat[cb+2]; bias4.w = bias_cat[cb+3];

  // co-residency check (bounded; no hang)
  if (tid == 0){
    __hip_atomic_fetch_add(&ctr[255], 1u, __ATOMIC_RELAXED, __HIP_MEMORY_SCOPE_AGENT);
    unsigned v = 0; int it = 0;
    do {
      v = __hip_atomic_load(&ctr[255], __ATOMIC_RELAXED, __HIP_MEMORY_SCOPE_AGENT);
      if (v >= 256u) break;
      __builtin_amdgcn_s_sleep(8);
    } while (++it < 2000000);
    okf = (v >= 256u) ? 1 : 0;
    sdead = 0;
  }
  __syncthreads();
  if (!okf) return;

  float cst = 0.f;
  int r16 = tid >> 4, q16 = tid & 15;

  // prologue: x-part for t=0
  f32x4 acc0, acc1;
  {
    bf16x8 xf[16];
    const bf16x8* xsrc = (const bf16x8*)(Xcat + ((long)0*128 + g*16 + (lane&15))*512 + (lane>>4)*8);
    #pragma unroll
    for (int s=0;s<16;s++) xf[s] = xsrc[s*4];
    acc0 = bias4;
    acc1.x=0.f; acc1.y=0.f; acc1.z=0.f; acc1.w=0.f;
    #pragma unroll
    for (int s=0;s<16;s+=2){
      acc0 = __builtin_amdgcn_mfma_f32_16x16x32_bf16(wf[s],   xf[s],   acc0, 0, 0, 0);
      acc1 = __builtin_amdgcn_mfma_f32_16x16x32_bf16(wf[s+1], xf[s+1], acc1, 0, 0, 0);
    }
  }

  #pragma unroll 1
  for (int t=0; t<1024; ++t){
    // ---- poll own 32 tagged words (units 4*q16+64*i+j of row r16); stage to LDS (r9 layout) ----
    if (t == 0){
      char* hl = actb;                      // h_0 = 0
      #pragma unroll
      for (int i=0;i<8;i++){
        int byt = (r16*1024 + q16*8 + i*128) ^ ((r16 & 7) << 4);
        *(ull*)(hl + byt) = 0ull;
      }
    } else {
      const unsigned* hp = hw + ((long)(t&1)*65536) + g*8192 + r16*512 + q16*4;
      u32x4 hv[8];
      unsigned tt = (unsigned)t; int itc = 0;
      for (;;){
        ld8x16_sc1(hp, hv);
        unsigned bad = 0;
        #pragma unroll
        for (int i=0;i<8;i++){
          bad |= (hv[i].x & 0xFFFFu) ^ tt;
          bad |= (hv[i].y & 0xFFFFu) ^ tt;
          bad |= (hv[i].z & 0xFFFFu) ^ tt;
          bad |= (hv[i].w & 0xFFFFu) ^ tt;
        }
        if (!bad) break;
        if ((itc & 31) == 31 && *(volatile int*)&sdead) break;
        if (++itc > 200000){
          *(volatile int*)&sdead = 1;
          __hip_atomic_store(&ctr[252], tt, __ATOMIC_RELAXED, __HIP_MEMORY_SCOPE_AGENT);
          break;
        }
      }
      // pack data (high 16) into bf16-pair words, write LDS with r9's exact pattern
      char* hl = actb + (t&1)*16384;
      #pragma unroll
      for (int i=0;i<8;i++){
        unsigned p0 = (hv[i].x >> 16) | (hv[i].y & 0xFFFF0000u);
        unsigned p1 = (hv[i].z >> 16) | (hv[i].w & 0xFFFF0000u);
        ull pp = (ull)p0 | ((ull)p1 << 32);
        int byt = (r16*1024 + q16*8 + i*128) ^ ((r16 & 7) << 4);
        *(ull*)(hl + byt) = pp;
      }
    }
    __syncthreads();
    if (*(volatile int*)&sdead) break;
    // ---- h-part MFMAs (k=512..1023) ----
    {
      const char* hl = actb + (t&1)*16384;
      #pragma unroll
      for (int s=0;s<16;s+=2){
        int by0 = ((lane&15)*1024 + s*64     + (lane>>4)*16) ^ (((lane&15)&7) << 4);
        int by1 = ((lane&15)*1024 + (s+1)*64 + (lane>>4)*16) ^ (((lane&15)&7) << 4);
        bf16x8 b0 = *(const bf16x8*)(hl + by0);
        bf16x8 b1 = *(const bf16x8*)(hl + by1);
        acc0 = __builtin_amdgcn_mfma_f32_16x16x32_bf16(wf[16+s], b0, acc0, 0, 0, 0);
        acc1 = __builtin_amdgcn_mfma_f32_16x16x32_bf16(wf[17+s], b1, acc1, 0, 0, 0);
      }
    }
    // ---- gates & state update ----
    float gi = acc0.x + acc1.x, gf = acc0.y + acc1.y;
    float gg = acc0.z + acc1.z, go = acc0.w + acc1.w;
    float iv = 1.f / (1.f + __expf(-gi));
    float fv = 1.f / (1.f + __expf(-gf));
    float e2 = __expf(-2.f * gg);
    float gv = (1.f - e2) / (1.f + e2);
    float ov = 1.f / (1.f + __expf(-go));
    cst = fv * cst + iv * gv;
    float e2c = __expf(-2.f * cst);
    float hout = ov * (1.f - e2c) / (1.f + e2c);
    // ---- publish h_{t+1} as tagged word (fire-and-forget) ----
    {
      unsigned short hb16 = f2bf(hout);
      int unit = 16*m + 4*w + (lane >> 4);
      int row  = lane & 15;
      unsigned word = ((unsigned)hb16 << 16) | (unsigned)(t+1);
      unsigned int* dst = hw + ((long)((t+1)&1)*65536) + g*8192 + row*512 + unit;
      __hip_atomic_store(dst, word, __ATOMIC_RELAXED, __HIP_MEMORY_SCOPE_AGENT);
    }
    // ---- x-part for t+1 (overlaps store visibility across the group) ----
    {
      int tn = (t < 1023) ? (t+1) : 1023;
      bf16x8 xf[16];
      const bf16x8* xsrc = (const bf16x8*)(Xcat + ((long)tn*128 + g*16 + (lane&15))*512 + (lane>>4)*8);
      #pragma unroll
      for (int s=0;s<16;s++) xf[s] = xsrc[s*4];
      acc0 = bias4;
      acc1.x=0.f; acc1.y=0.f; acc1.z=0.f; acc1.w=0.f;
      #pragma unroll
      for (int s=0;s<16;s+=2){
        acc0 = __builtin_amdgcn_mfma_f32_16x16x32_bf16(wf[s],   xf[s],   acc0, 0, 0, 0);
        acc1 = __builtin_amdgcn_mfma_f32_16x16x32_bf16(wf[s+1], xf[s+1], acc1, 0, 0, 0);
      }
    }
  }

  __syncthreads();
  if (tid == 0 && !sdead)
    __hip_atomic_fetch_add(&ctr[251], 1u, __ATOMIC_RELAXED, __HIP_MEMORY_SCOPE_AGENT);
}

// ---------------- output projection (reads tagged words, parity 0) ----------------
__global__ void __launch_bounds__(256) out_gemm(
    const unsigned int* __restrict__ hw, const unsigned int* __restrict__ ctr,
    const float* __restrict__ out_w, const float* __restrict__ out_b,
    float* __restrict__ out){
  unsigned done = ctr[251], arriv = ctr[255], dead = ctr[252];
  if (dead != 0u || done != 256u){
    float v = dead ? (20000.f + (float)dead) : (10000.f + (float)arriv);
    if (threadIdx.x < 32) out[blockIdx.x*32 + threadIdx.x] = v;
    return;
  }
  __shared__ float part[8][32];
  int b = blockIdx.x;
  int g = b >> 4, r = b & 15;
  const unsigned int* hrow = hw + (long)g*8192 + r*512;   // parity 0 holds h after step 1023
  int col = threadIdx.x & 31, p = threadIdx.x >> 5;
  float s = 0.f;
  for (int u = p*64; u < p*64 + 64; ++u)
    s += bf2f((unsigned short)(hrow[u] >> 16)) * out_w[col*512 + u];
  part[p][col] = s;
  __syncthreads();
  if (p == 0){
    float t = out_b[col];
    #pragma unroll
    for (int i=0;i<8;i++) t += part[i][col];
    out[b*32 + col] = t;
  }
}

extern "C" void kernel_launch(void* const* d_in, const int* in_sizes, int n_in,
                              void* d_out, int out_size, void* d_ws, size_t ws_size,
                              hipStream_t stream){
  const float* x_num   = (const float*)d_in[0];
  const int*   x_state = (const int*)d_in[1];
  const float* num_w0  = (const float*)d_in[2];
  const float* num_b0  = (const float*)d_in[3];
  const float* num_w1  = (const float*)d_in[4];
  const float* num_b1  = (const float*)d_in[5];
  const float* emb     = (const float*)d_in[6];
  const float* st_w0   = (const float*)d_in[7];
  const float* st_b0   = (const float*)d_in[8];
  const float* st_w1   = (const float*)d_in[9];
  const float* st_b1   = (const float*)d_in[10];
  const float* Wii = (const float*)d_in[11];
  const float* Whi = (const float*)d_in[12];
  const float* Wif = (const float*)d_in[13];
  const float* Whf = (const float*)d_in[14];
  const float* Wig = (const float*)d_in[15];
  const float* Whg = (const float*)d_in[16];
  const float* Wio = (const float*)d_in[17];
  const float* Who = (const float*)d_in[18];
  const float* Bii = (const float*)d_in[19];
  const float* Bhi = (const float*)d_in[20];
  const float* Bif = (const float*)d_in[21];
  const float* Bhf = (const float*)d_in[22];
  const float* Big = (const float*)d_in[23];
  const float* Bhg = (const float*)d_in[24];
  const float* Bio = (const float*)d_in[25];
  const float* Bho = (const float*)d_in[26];
  const float* out_w = (const float*)d_in[27];
  const float* out_b = (const float*)d_in[28];

  float* out = (float*)d_out;

  // sentinel: if later launches silently fail, absmax ~= 50000
  diag_write<<<16, 256, 0, stream>>>(out, 50000.f);

  if (ws_size < WS_NEED){
    diag_write<<<16, 256, 0, stream>>>(out, 100000.f + (float)(ws_size >> 20));
    return;
  }

  char* ws = (char*)d_ws;
  unsigned short* Xcat = (unsigned short*)(ws + OFF_XCAT);
  unsigned short* Wcat = (unsigned short*)(ws + OFF_WCAT);
  float* bias_cat      = (float*)(ws + OFF_BIAS);
  unsigned int* hw     = (unsigned int*)(ws + OFF_HW);
  unsigned int* ctr    = (unsigned int*)(ws + OFF_CTR);

  // zero tagged-word h buffer + counters every call (tags restart at 1)
  hipMemsetAsync(ws + OFF_HW, 0, 524288 + 1024, stream);

  prep_w<<<8192, 256, 0, stream>>>(Wii, Wif, Wig, Wio, Whi, Whf, Whg, Who,
                                   Bii, Bif, Big, Bio, Bhi, Bhf, Bhg, Bho,
                                   Wcat, bias_cat);

  stageA_fused<<<8192, 256, 0, stream>>>(x_num, x_state, emb,
                                         num_w0, num_b0, num_w1, num_b1,
                                         st_w0, st_b0, st_w1, st_b1, Xcat);

  lstm_pk<<<256, 256, 0, stream>>>(Xcat, Wcat, bias_cat, hw, ctr);

  out_gemm<<<128, 256, 0, stream>>>(hw, ctr, out_w, out_b, out);
}